// Round 1
// baseline (2622.273 us; speedup 1.0000x reference)
//
#include <hip/hip_runtime.h>
#include <cstdint>
#include <cstddef>

#define N_NODES  30000
#define N_EDGES  480000
#define N_LAYERS 3
#define N_GRAPHS 64
#define N_CLASS  10

// ===================== GEMM: C[Mx128] = A[Mx128] @ W[128x128] + bias ========
// MODE 0: plain GEMM + bias -> Cout
// MODE 1: edge message: en = acc + bias + Dh[src] + Eh[dst]; write Cout(=e_new);
//         accumulate BN stats of (en * snorm_e) into stSum/stSq (global atomics)
template<int MODE>
__global__ __launch_bounds__(256)
void gemm128(const float* __restrict__ A, const float* __restrict__ W,
             const float* __restrict__ bias, float* __restrict__ Cout, int M,
             const int* __restrict__ src, const int* __restrict__ dst,
             const float* __restrict__ Dh, const float* __restrict__ Eh,
             const float* __restrict__ snorm, float* __restrict__ stSum,
             float* __restrict__ stSq)
{
  __shared__ float As[128][33];   // [row][k], +1 pad -> conflict-free scalar reads
  __shared__ float Ws[32][128];   // [k][n]
  __shared__ float sSum[128];
  __shared__ float sSq[128];
  const int t  = threadIdx.x;
  const int tx = t & 15;          // col group: cols {4tx..4tx+3} u {64+4tx..}
  const int ty = t >> 4;          // row group: rows 8ty..8ty+7
  const int row0 = blockIdx.x * 128;

  float acc[8][8];
#pragma unroll
  for (int i = 0; i < 8; ++i)
#pragma unroll
    for (int j = 0; j < 8; ++j) acc[i][j] = 0.f;

  for (int kk = 0; kk < 128; kk += 32) {
    { // stage A tile (128 rows x 32 k)
      const int f = t & 7, r = t >> 3;
#pragma unroll
      for (int p = 0; p < 4; ++p) {
        const int rl = 32*p + r;
        const int grow = row0 + rl;
        float4 v = make_float4(0.f, 0.f, 0.f, 0.f);
        if (grow < M) v = *(const float4*)(A + (size_t)grow*128 + kk + 4*f);
        As[rl][4*f+0] = v.x; As[rl][4*f+1] = v.y;
        As[rl][4*f+2] = v.z; As[rl][4*f+3] = v.w;
      }
    }
    { // stage W tile (32 k x 128 n)
      const int n4 = t & 31, kr = t >> 5;
#pragma unroll
      for (int q = 0; q < 4; ++q) {
        const int kl = kr + 8*q;
        *(float4*)&Ws[kl][4*n4] = *(const float4*)(W + (size_t)(kk+kl)*128 + 4*n4);
      }
    }
    __syncthreads();
#pragma unroll
    for (int k = 0; k < 32; ++k) {
      float a[8];
#pragma unroll
      for (int i = 0; i < 8; ++i) a[i] = As[8*ty+i][k];
      const float4 b0 = *(const float4*)&Ws[k][4*tx];
      const float4 b1 = *(const float4*)&Ws[k][64 + 4*tx];
      const float b[8] = {b0.x,b0.y,b0.z,b0.w,b1.x,b1.y,b1.z,b1.w};
#pragma unroll
      for (int i = 0; i < 8; ++i)
#pragma unroll
        for (int j = 0; j < 8; ++j) acc[i][j] = fmaf(a[i], b[j], acc[i][j]);
    }
    __syncthreads();
  }

  const float4 bq0 = *(const float4*)(bias + 4*tx);
  const float4 bq1 = *(const float4*)(bias + 64 + 4*tx);
  const float bb[8] = {bq0.x,bq0.y,bq0.z,bq0.w,bq1.x,bq1.y,bq1.z,bq1.w};

  if (MODE == 0) {
#pragma unroll
    for (int i = 0; i < 8; ++i) {
      const int r = row0 + 8*ty + i;
      if (r < M) {
        *(float4*)(Cout + (size_t)r*128 + 4*tx) =
          make_float4(acc[i][0]+bb[0], acc[i][1]+bb[1], acc[i][2]+bb[2], acc[i][3]+bb[3]);
        *(float4*)(Cout + (size_t)r*128 + 64 + 4*tx) =
          make_float4(acc[i][4]+bb[4], acc[i][5]+bb[5], acc[i][6]+bb[6], acc[i][7]+bb[7]);
      }
    }
  } else {
    if (t < 128) { sSum[t] = 0.f; sSq[t] = 0.f; }
    __syncthreads();
    float ps[8] = {0,0,0,0,0,0,0,0};
    float pq[8] = {0,0,0,0,0,0,0,0};
#pragma unroll
    for (int i = 0; i < 8; ++i) {
      const int r = row0 + 8*ty + i;
      if (r < M) {
        const int s = src[r], d = dst[r];
        const float sn = snorm[r];
        const float* Ds = Dh + (size_t)s*128;
        const float* Es = Eh + (size_t)d*128;
        const float4 d0 = *(const float4*)(Ds + 4*tx);
        const float4 d1 = *(const float4*)(Ds + 64 + 4*tx);
        const float4 e0 = *(const float4*)(Es + 4*tx);
        const float4 e1 = *(const float4*)(Es + 64 + 4*tx);
        const float dv[8] = {d0.x,d0.y,d0.z,d0.w,d1.x,d1.y,d1.z,d1.w};
        const float ev[8] = {e0.x,e0.y,e0.z,e0.w,e1.x,e1.y,e1.z,e1.w};
        float en[8];
#pragma unroll
        for (int j = 0; j < 8; ++j) {
          en[j] = acc[i][j] + bb[j] + dv[j] + ev[j];
          const float tv = en[j] * sn;
          ps[j] += tv; pq[j] = fmaf(tv, tv, pq[j]);
        }
        *(float4*)(Cout + (size_t)r*128 + 4*tx)      = make_float4(en[0],en[1],en[2],en[3]);
        *(float4*)(Cout + (size_t)r*128 + 64 + 4*tx) = make_float4(en[4],en[5],en[6],en[7]);
      }
    }
#pragma unroll
    for (int j = 0; j < 4; ++j) {
      atomicAdd(&sSum[4*tx+j],    ps[j]);
      atomicAdd(&sSq [4*tx+j],    pq[j]);
      atomicAdd(&sSum[64+4*tx+j], ps[4+j]);
      atomicAdd(&sSq [64+4*tx+j], pq[4+j]);
    }
    __syncthreads();
    if (t < 128) { atomicAdd(stSum + t, sSum[t]); atomicAdd(stSq + t, sSq[t]); }
  }
}

// ===================== CSR build ============================================
__global__ void hist_kernel(const int* __restrict__ dst, int* __restrict__ cnt, int E)
{
  const int i = blockIdx.x*256 + threadIdx.x;
  if (i < E) atomicAdd(&cnt[dst[i]], 1);
}

__global__ void scan_kernel(const int* __restrict__ cnt, int* __restrict__ start,
                            int* __restrict__ cursor, int n, int total)
{
  __shared__ int lds[1024];
  const int tid = threadIdx.x;
  const int chunk = (n + 1023) / 1024;
  const int lo = tid * chunk, hi = min(lo + chunk, n);
  int s = 0;
  for (int i = lo; i < hi; ++i) s += cnt[i];
  lds[tid] = s;
  __syncthreads();
  for (int off = 1; off < 1024; off <<= 1) {
    const int v = (tid >= off) ? lds[tid - off] : 0;
    __syncthreads();
    lds[tid] += v;
    __syncthreads();
  }
  int run = (tid == 0) ? 0 : lds[tid - 1];
  for (int i = lo; i < hi; ++i) { start[i] = run; cursor[i] = run; run += cnt[i]; }
  if (tid == 0) start[n] = total;
}

__global__ void scatter_kernel(const int* __restrict__ dst, int* __restrict__ cursor,
                               int* __restrict__ csr, int E)
{
  const int i = blockIdx.x*256 + threadIdx.x;
  if (i < E) { const int p = atomicAdd(&cursor[dst[i]], 1); csr[p] = i; }
}

// ===================== per-node gated reduce (no atomics) ===================
// h_new_pre_bn = (Ah + num/(den+1e-6)) * snorm_n   -> tbuf
__global__ void reduce_kernel(const float* __restrict__ enew, const float* __restrict__ Bh,
                              const float* __restrict__ Ah, const float* __restrict__ snorm_n,
                              const int* __restrict__ start, const int* __restrict__ csr,
                              const int* __restrict__ src, float* __restrict__ tbuf)
{
  const int v = blockIdx.x;
  const int c = threadIdx.x;                 // 128 threads = column
  __shared__ int s_eid[64];
  __shared__ int s_src[64];
  const int s0 = start[v], s1 = start[v+1];
  float num = 0.f, den = 0.f;
  for (int base = s0; base < s1; base += 64) {
    const int m = min(64, s1 - base);
    if (c < m) { const int eid = csr[base + c]; s_eid[c] = eid; s_src[c] = src[eid]; }
    __syncthreads();
    for (int j = 0; j < m; ++j) {
      const float en  = enew[(size_t)s_eid[j]*128 + c];
      const float sig = 1.f / (1.f + expf(-en));
      num = fmaf(sig, Bh[(size_t)s_src[j]*128 + c], num);
      den += sig;
    }
    __syncthreads();
  }
  tbuf[(size_t)v*128 + c] = (Ah[(size_t)v*128 + c] + num / (den + 1e-6f)) * snorm_n[v];
}

// ===================== BN stats over node tensor ============================
__global__ void stats_kernel(const float* __restrict__ x, int M,
                             float* __restrict__ outSum, float* __restrict__ outSq)
{
  const int c  = threadIdx.x & 127;
  const int rl = threadIdx.x >> 7;           // 0..1
  const int stride = gridDim.x * 2;
  float s = 0.f, q = 0.f;
  for (int r = blockIdx.x*2 + rl; r < M; r += stride) {
    const float v = x[(size_t)r*128 + c];
    s += v; q = fmaf(v, v, q);
  }
  __shared__ float ls[2][128], lq[2][128];
  ls[rl][c] = s; lq[rl][c] = q;
  __syncthreads();
  if (rl == 0) {
    atomicAdd(outSum + c, ls[0][c] + ls[1][c]);
    atomicAdd(outSq + c,  lq[0][c] + lq[1][c]);
  }
}

// stats layout: [0]sumH [128]sqH [256]sumE [384]sqE [512]muH [640]invH [768]muE [896]invE
__global__ void finalize_kernel(float* __restrict__ stats, float invN, float invE)
{
  const int c = threadIdx.x;
  if (c < 128) {
    const float muH = stats[c] * invN;
    const float vH  = fmaxf(stats[128+c]*invN - muH*muH, 0.f);
    const float muE = stats[256+c] * invE;
    const float vE  = fmaxf(stats[384+c]*invE - muE*muE, 0.f);
    stats[512+c] = muH;
    stats[640+c] = rsqrtf(vH + 1e-5f);
    stats[768+c] = muE;
    stats[896+c] = rsqrtf(vE + 1e-5f);
  }
}

// ===================== BN apply + ReLU + residual ===========================
__global__ void node_apply(float* __restrict__ h, const float* __restrict__ tb,
                           const float* __restrict__ muinv, const float* __restrict__ gn,
                           const float* __restrict__ bt, int M)
{
  const int total = M * 32;                  // float4 count
  for (int i = blockIdx.x*blockDim.x + threadIdx.x; i < total; i += gridDim.x*blockDim.x) {
    const int c0 = (i & 31) * 4;
    const float4 tv = *(const float4*)(tb + (size_t)i*4);
    float4 hv = *(float4*)(h + (size_t)i*4);
    const float tt[4] = {tv.x, tv.y, tv.z, tv.w};
    float hh[4] = {hv.x, hv.y, hv.z, hv.w};
#pragma unroll
    for (int j = 0; j < 4; ++j) {
      const int c = c0 + j;
      const float x = (tt[j] - muinv[c]) * muinv[128+c] * gn[c] + bt[c];
      hh[j] += fmaxf(x, 0.f);
    }
    *(float4*)(h + (size_t)i*4) = make_float4(hh[0], hh[1], hh[2], hh[3]);
  }
}

__global__ void edge_apply(float* __restrict__ e, const float* __restrict__ enew,
                           const float* __restrict__ snorm, const float* __restrict__ muinv,
                           const float* __restrict__ gn, const float* __restrict__ bt, int M)
{
  const int total = M * 32;
  for (int i = blockIdx.x*blockDim.x + threadIdx.x; i < total; i += gridDim.x*blockDim.x) {
    const int row = i >> 5;
    const int c0  = (i & 31) * 4;
    const float sn = snorm[row];
    const float4 tv = *(const float4*)(enew + (size_t)i*4);
    float4 ev = *(float4*)(e + (size_t)i*4);
    const float tt[4] = {tv.x, tv.y, tv.z, tv.w};
    float ee[4] = {ev.x, ev.y, ev.z, ev.w};
#pragma unroll
    for (int j = 0; j < 4; ++j) {
      const int c = c0 + j;
      const float x = (tt[j]*sn - muinv[256+c]) * muinv[384+c] * gn[c] + bt[c];
      ee[j] += fmaxf(x, 0.f);
    }
    *(float4*)(e + (size_t)i*4) = make_float4(ee[0], ee[1], ee[2], ee[3]);
  }
}

// ===================== readout ==============================================
__global__ void readout_scatter(const float* __restrict__ h, const int* __restrict__ gid,
                                float* __restrict__ gsum, int* __restrict__ gcnt, int N)
{
  const int c = threadIdx.x;                 // 128
  const int row0 = blockIdx.x * 256;
  int cur = -1, cnt = 0;
  float s = 0.f;
  for (int r = 0; r < 256; ++r) {
    const int v = row0 + r;
    if (v >= N) break;
    const int g = gid[v];
    if (g != cur) {
      if (cur >= 0) {
        atomicAdd(&gsum[(size_t)cur*128 + c], s);
        if (c == 0) atomicAdd(&gcnt[cur], cnt);
      }
      cur = g; s = 0.f; cnt = 0;
    }
    s += h[(size_t)v*128 + c];
    ++cnt;
  }
  if (cur >= 0) {
    atomicAdd(&gsum[(size_t)cur*128 + c], s);
    if (c == 0) atomicAdd(&gcnt[cur], cnt);
  }
}

__global__ void readout_final(const float* __restrict__ gsum, const int* __restrict__ gcnt,
                              const float* __restrict__ Wr, const float* __restrict__ br,
                              float* __restrict__ out)
{
  const int g = blockIdx.x;
  const int t = threadIdx.x;                 // 128
  __shared__ float hg[128];
  const float cnt = fmaxf((float)gcnt[g], 1.f);
  hg[t] = gsum[(size_t)g*128 + t] / cnt;
  __syncthreads();
  if (t < N_CLASS) {
    float acc = br[t];
    for (int k = 0; k < 128; ++k) acc = fmaf(hg[k], Wr[k*N_CLASS + t], acc);
    out[g*N_CLASS + t] = acc;
  }
}

// ===================== launcher =============================================
extern "C" void kernel_launch(void* const* d_in, const int* in_sizes, int n_in,
                              void* d_out, int out_size, void* d_ws, size_t ws_size,
                              hipStream_t stream)
{
  const float* h_in    = (const float*)d_in[0];
  const float* e_in    = (const float*)d_in[1];
  const float* snorm_n = (const float*)d_in[2];
  const float* snorm_e = (const float*)d_in[3];
  const int*   src     = (const int*)d_in[4];
  const int*   dst     = (const int*)d_in[5];
  const int*   gid     = (const int*)d_in[6];
  const float* Wh_emb  = (const float*)d_in[7];
  const float* bh_emb  = (const float*)d_in[8];
  const float* We_emb  = (const float*)d_in[9];
  const float* be_emb  = (const float*)d_in[10];
  const float* WA = (const float*)d_in[11]; const float* bA = (const float*)d_in[12];
  const float* WB = (const float*)d_in[13]; const float* bB = (const float*)d_in[14];
  const float* WC = (const float*)d_in[15]; const float* bC = (const float*)d_in[16];
  const float* WD = (const float*)d_in[17]; const float* bD = (const float*)d_in[18];
  const float* WE = (const float*)d_in[19]; const float* bE = (const float*)d_in[20];
  const float* gn_h = (const float*)d_in[21]; const float* bt_h = (const float*)d_in[22];
  const float* gn_e = (const float*)d_in[23]; const float* bt_e = (const float*)d_in[24];
  const float* Wr = (const float*)d_in[25]; const float* br = (const float*)d_in[26];
  float* out = (float*)d_out;
  (void)in_sizes; (void)n_in; (void)out_size; (void)ws_size;

  char* ws = (char*)d_ws;
  size_t off = 0;
  auto alloc = [&](size_t bytes) -> char* {
    off = (off + 255) & ~(size_t)255;
    char* p = ws + off;
    off += bytes;
    return p;
  };
  const size_t ND = (size_t)N_NODES * 128, ED = (size_t)N_EDGES * 128;
  float* hbuf  = (float*)alloc(ND * 4);
  float* ebuf  = (float*)alloc(ED * 4);
  float* enew  = (float*)alloc(ED * 4);
  float* Ah    = (float*)alloc(ND * 4);
  float* Bh    = (float*)alloc(ND * 4);
  float* Dh    = (float*)alloc(ND * 4);
  float* Eh    = (float*)alloc(ND * 4);
  float* tbuf  = (float*)alloc(ND * 4);
  float* stats = (float*)alloc(1024 * 4);
  int* cnt     = (int*)alloc((size_t)N_NODES * 4);
  int* start   = (int*)alloc((size_t)(N_NODES + 1) * 4);
  int* cursor  = (int*)alloc((size_t)N_NODES * 4);
  int* csr     = (int*)alloc((size_t)N_EDGES * 4);
  float* gsum  = (float*)alloc((size_t)N_GRAPHS * 128 * 4);
  int* gcnt    = (int*)alloc((size_t)N_GRAPHS * 4);

  // ---- CSR by dst (src/dst fixed across layers -> build once per call) ----
  hipMemsetAsync(cnt, 0, (size_t)N_NODES * 4, stream);
  hist_kernel<<<(N_EDGES + 255) / 256, 256, 0, stream>>>(dst, cnt, N_EDGES);
  scan_kernel<<<1, 1024, 0, stream>>>(cnt, start, cursor, N_NODES, N_EDGES);
  scatter_kernel<<<(N_EDGES + 255) / 256, 256, 0, stream>>>(dst, cursor, csr, N_EDGES);

  const int gbN = (N_NODES + 127) / 128;   // 235
  const int gbE = (N_EDGES + 127) / 128;   // 3750

  // ---- input embeddings ----
  gemm128<0><<<gbN, 256, 0, stream>>>(h_in, Wh_emb, bh_emb, hbuf, N_NODES,
                                      nullptr, nullptr, nullptr, nullptr, nullptr, nullptr, nullptr);
  gemm128<0><<<gbE, 256, 0, stream>>>(e_in, We_emb, be_emb, ebuf, N_EDGES,
                                      nullptr, nullptr, nullptr, nullptr, nullptr, nullptr, nullptr);

  for (int l = 0; l < N_LAYERS; ++l) {
    const size_t wOff = (size_t)l * 128 * 128;
    const size_t bOff = (size_t)l * 128;
    gemm128<0><<<gbN, 256, 0, stream>>>(hbuf, WA + wOff, bA + bOff, Ah, N_NODES,
                                        nullptr, nullptr, nullptr, nullptr, nullptr, nullptr, nullptr);
    gemm128<0><<<gbN, 256, 0, stream>>>(hbuf, WB + wOff, bB + bOff, Bh, N_NODES,
                                        nullptr, nullptr, nullptr, nullptr, nullptr, nullptr, nullptr);
    gemm128<0><<<gbN, 256, 0, stream>>>(hbuf, WD + wOff, bD + bOff, Dh, N_NODES,
                                        nullptr, nullptr, nullptr, nullptr, nullptr, nullptr, nullptr);
    gemm128<0><<<gbN, 256, 0, stream>>>(hbuf, WE + wOff, bE + bOff, Eh, N_NODES,
                                        nullptr, nullptr, nullptr, nullptr, nullptr, nullptr, nullptr);
    hipMemsetAsync(stats, 0, 512 * 4, stream);
    gemm128<1><<<gbE, 256, 0, stream>>>(ebuf, WC + wOff, bC + bOff, enew, N_EDGES,
                                        src, dst, Dh, Eh, snorm_e, stats + 256, stats + 384);
    reduce_kernel<<<N_NODES, 128, 0, stream>>>(enew, Bh, Ah, snorm_n, start, csr, src, tbuf);
    stats_kernel<<<128, 256, 0, stream>>>(tbuf, N_NODES, stats + 0, stats + 128);
    finalize_kernel<<<1, 128, 0, stream>>>(stats, 1.f / N_NODES, 1.f / N_EDGES);
    node_apply<<<2048, 256, 0, stream>>>(hbuf, tbuf, stats + 512, gn_h + bOff, bt_h + bOff, N_NODES);
    edge_apply<<<4096, 256, 0, stream>>>(ebuf, enew, snorm_e, stats + 512, gn_e + bOff, bt_e + bOff, N_EDGES);
  }

  // ---- readout ----
  hipMemsetAsync(gsum, 0, (size_t)N_GRAPHS * 128 * 4, stream);
  hipMemsetAsync(gcnt, 0, (size_t)N_GRAPHS * 4, stream);
  readout_scatter<<<(N_NODES + 255) / 256, 128, 0, stream>>>(hbuf, gid, gsum, gcnt, N_NODES);
  readout_final<<<N_GRAPHS, 128, 0, stream>>>(gsum, gcnt, Wr, br, out);
}

// Round 2
// 1491.900 us; speedup vs baseline: 1.7577x; 1.7577x over previous
//
#include <hip/hip_runtime.h>
#include <cstdint>
#include <cstddef>

#define N_NODES  30000
#define N_EDGES  480000
#define N_LAYERS 3
#define N_GRAPHS 64
#define N_CLASS  10
#define NREP     32

typedef __attribute__((ext_vector_type(8))) short short8v;   // 8 bf16 (4 VGPR)
typedef __attribute__((ext_vector_type(4))) float f32x4;

__device__ __forceinline__ unsigned short f2bf(float x) {
  union { float f; unsigned u; } v; v.f = x;
  unsigned r = v.u + 0x7FFFu + ((v.u >> 16) & 1u);   // RNE
  return (unsigned short)(r >> 16);
}
__device__ __forceinline__ float bf2f(unsigned short h) {
  union { unsigned u; float f; } v; v.u = ((unsigned)h) << 16;
  return v.f;
}

// ============ weight convert + transpose: Wt[mi][n][k] = bf16(W[k][n]) ======
// mi: 0=Wh_emb 1=We_emb 2+l=WA 5+l=WB 8+l=WC 11+l=WD 14+l=WE
__global__ void wconv(const float* __restrict__ Wh, const float* __restrict__ We,
                      const float* __restrict__ WA, const float* __restrict__ WB,
                      const float* __restrict__ WC, const float* __restrict__ WD,
                      const float* __restrict__ WE, unsigned short* __restrict__ Wt)
{
  const int mi  = blockIdx.x >> 6;
  const int idx = (blockIdx.x & 63) * 256 + threadIdx.x;   // 0..16383
  const float* src;
  if      (mi == 0) src = Wh;
  else if (mi == 1) src = We;
  else if (mi < 5)  src = WA + (size_t)(mi - 2) * 16384;
  else if (mi < 8)  src = WB + (size_t)(mi - 5) * 16384;
  else if (mi < 11) src = WC + (size_t)(mi - 8) * 16384;
  else if (mi < 14) src = WD + (size_t)(mi - 11) * 16384;
  else              src = WE + (size_t)(mi - 14) * 16384;
  const int k = idx >> 7, n = idx & 127;
  Wt[(size_t)mi * 16384 + (size_t)n * 128 + k] = f2bf(src[idx]);
}

// ============ MFMA GEMM: out_m = A @ W_m + b_m (NMAT outputs share A) =======
struct GemmArgs {
  const unsigned short* Wt[4];
  const float* bias[4];
  unsigned short* out[4];
};

template<int NMAT, bool AFP32>
__global__ __launch_bounds__(256)
void gemm_mm(const void* __restrict__ Ap, GemmArgs g, int M)
{
  const int t = threadIdx.x;
  const int w = t >> 6, l = t & 63;
  const int lr = l & 15, lk = (l >> 4) * 8;
  const int r0 = blockIdx.x * 64 + w * 16;
  int arow = r0 + lr; if (arow >= M) arow = M - 1;

  short8v a[4];
  if (AFP32) {
    const float* A = (const float*)Ap;
#pragma unroll
    for (int kk = 0; kk < 4; ++kk) {
      const float* p = A + (size_t)arow * 128 + kk * 32 + lk;
      const float4 u = *(const float4*)p;
      const float4 v = *(const float4*)(p + 4);
      short8v av;
      av[0]=f2bf(u.x); av[1]=f2bf(u.y); av[2]=f2bf(u.z); av[3]=f2bf(u.w);
      av[4]=f2bf(v.x); av[5]=f2bf(v.y); av[6]=f2bf(v.z); av[7]=f2bf(v.w);
      a[kk] = av;
    }
  } else {
    const unsigned short* A = (const unsigned short*)Ap;
#pragma unroll
    for (int kk = 0; kk < 4; ++kk)
      a[kk] = *(const short8v*)(A + (size_t)arow * 128 + kk * 32 + lk);
  }

#pragma unroll
  for (int m = 0; m < NMAT; ++m) {
    const unsigned short* Wt = g.Wt[m];
    f32x4 acc[8];
#pragma unroll
    for (int ct = 0; ct < 8; ++ct) acc[ct] = (f32x4){0.f, 0.f, 0.f, 0.f};
#pragma unroll
    for (int kk = 0; kk < 4; ++kk) {
#pragma unroll
      for (int ct = 0; ct < 8; ++ct) {
        const short8v b = *(const short8v*)(Wt + (size_t)(ct * 16 + lr) * 128 + kk * 32 + lk);
        acc[ct] = __builtin_amdgcn_mfma_f32_16x16x32_bf16(a[kk], b, acc[ct], 0, 0, 0);
      }
    }
    const float* bias = g.bias[m];
    unsigned short* out = g.out[m];
    const int rbase = r0 + (l >> 4) * 4;
#pragma unroll
    for (int ct = 0; ct < 8; ++ct) {
      const float bb = bias[ct * 16 + lr];
#pragma unroll
      for (int q = 0; q < 4; ++q) {
        const int rr = rbase + q;
        if (rr < M) out[(size_t)rr * 128 + ct * 16 + lr] = f2bf(acc[ct][q] + bb);
      }
    }
  }
}

// ============ edge GEMM: enew = ebuf@WC + bC + Dh[src] + Eh[dst] (raw) ======
__global__ __launch_bounds__(256)
void gemm_edge(const unsigned short* __restrict__ ebuf, const unsigned short* __restrict__ WtC,
               const float* __restrict__ bC, const unsigned short* __restrict__ Dh,
               const unsigned short* __restrict__ Eh, const int* __restrict__ src,
               const int* __restrict__ dst, unsigned short* __restrict__ enew)
{
  __shared__ float st[64][132];
  const int t = threadIdx.x;
  const int w = t >> 6, l = t & 63;
  const int lr = l & 15, lk = (l >> 4) * 8;
  const int r0 = blockIdx.x * 64 + w * 16;   // E % 64 == 0: no guards

  short8v a[4];
#pragma unroll
  for (int kk = 0; kk < 4; ++kk)
    a[kk] = *(const short8v*)(ebuf + (size_t)(r0 + lr) * 128 + kk * 32 + lk);

  f32x4 acc[8];
#pragma unroll
  for (int ct = 0; ct < 8; ++ct) acc[ct] = (f32x4){0.f, 0.f, 0.f, 0.f};
#pragma unroll
  for (int kk = 0; kk < 4; ++kk) {
#pragma unroll
    for (int ct = 0; ct < 8; ++ct) {
      const short8v b = *(const short8v*)(WtC + (size_t)(ct * 16 + lr) * 128 + kk * 32 + lk);
      acc[ct] = __builtin_amdgcn_mfma_f32_16x16x32_bf16(a[kk], b, acc[ct], 0, 0, 0);
    }
  }
  // transpose through LDS (+bias)
  const int lrow = w * 16 + (l >> 4) * 4;
#pragma unroll
  for (int ct = 0; ct < 8; ++ct) {
    const float bb = bC[ct * 16 + lr];
#pragma unroll
    for (int q = 0; q < 4; ++q) st[lrow + q][ct * 16 + lr] = acc[ct][q] + bb;
  }
  __syncthreads();
  // epilogue: thread -> (row, 32-col slice); vectorized gathers + write
  const int rr = t >> 2, c0 = (t & 3) * 32;
  const int edge = blockIdx.x * 64 + rr;
  const int s = src[edge], d = dst[edge];
  const unsigned short* Dp = Dh + (size_t)s * 128 + c0;
  const unsigned short* Ep = Eh + (size_t)d * 128 + c0;
  unsigned short ob[32];
#pragma unroll
  for (int gg = 0; gg < 4; ++gg) {
    const short8v dv = *(const short8v*)(Dp + gg * 8);
    const short8v ev = *(const short8v*)(Ep + gg * 8);
#pragma unroll
    for (int j = 0; j < 8; ++j) {
      const float en = st[rr][c0 + gg * 8 + j] + bf2f((unsigned short)dv[j]) + bf2f((unsigned short)ev[j]);
      ob[gg * 8 + j] = f2bf(en);
    }
  }
#pragma unroll
  for (int gg = 0; gg < 4; ++gg)
    *(short8v*)(enew + (size_t)edge * 128 + c0 + gg * 8) = *(const short8v*)(ob + gg * 8);
}

// ============ CSR build =====================================================
__global__ void hist_kernel(const int* __restrict__ dst, int* __restrict__ cnt, int E)
{
  const int i = blockIdx.x * 256 + threadIdx.x;
  if (i < E) atomicAdd(&cnt[dst[i]], 1);
}

__global__ void scan_kernel(const int* __restrict__ cnt, int* __restrict__ start,
                            int* __restrict__ cursor, int n, int total)
{
  __shared__ int lds[1024];
  const int tid = threadIdx.x;
  const int chunk = (n + 1023) / 1024;
  const int lo = tid * chunk, hi = min(lo + chunk, n);
  int s = 0;
  for (int i = lo; i < hi; ++i) s += cnt[i];
  lds[tid] = s;
  __syncthreads();
  for (int off = 1; off < 1024; off <<= 1) {
    const int v = (tid >= off) ? lds[tid - off] : 0;
    __syncthreads();
    lds[tid] += v;
    __syncthreads();
  }
  int run = (tid == 0) ? 0 : lds[tid - 1];
  for (int i = lo; i < hi; ++i) { start[i] = run; cursor[i] = run; run += cnt[i]; }
  if (tid == 0) start[n] = total;
}

__global__ void scatter_kernel(const int* __restrict__ dst, int* __restrict__ cursor,
                               int* __restrict__ csr, int E)
{
  const int i = blockIdx.x * 256 + threadIdx.x;
  if (i < E) { const int p = atomicAdd(&cursor[dst[i]], 1); csr[p] = i; }
}

// ============ aggregate: gated reduce + BN stats (h and e) ==================
// 8 nodes per block, 128 threads (thread = column). Every edge appears exactly
// once in CSR -> edge BN stats accumulated here, not in the GEMM.
__global__ __launch_bounds__(128)
void aggregate(const unsigned short* __restrict__ enew, const unsigned short* __restrict__ Bh,
               const unsigned short* __restrict__ Ah, const float* __restrict__ snorm_n,
               const float* __restrict__ snorm_e, const int* __restrict__ start,
               const int* __restrict__ csr, const int* __restrict__ src,
               float* __restrict__ tbuf, float* __restrict__ statrep, int doE)
{
  const int c = threadIdx.x;
  __shared__ int   s_eid[128];
  __shared__ int   s_src[128];
  __shared__ float s_sne[128];
  float psH = 0.f, pqH = 0.f, psE = 0.f, pqE = 0.f;
  const int v0 = blockIdx.x * 8;
  for (int vi = 0; vi < 8; ++vi) {
    const int v = v0 + vi;
    const int s0 = start[v], s1 = start[v + 1];
    float num = 0.f, den = 0.f;
    for (int base = s0; base < s1; base += 128) {
      const int m = min(128, s1 - base);
      if (c < m) {
        const int eid = csr[base + c];
        s_eid[c] = eid; s_src[c] = src[eid]; s_sne[c] = snorm_e[eid];
      }
      __syncthreads();
      for (int j = 0; j < m; ++j) {
        const float en  = bf2f(enew[(size_t)s_eid[j] * 128 + c]);
        const float sig = 1.f / (1.f + __expf(-en));
        num = fmaf(sig, bf2f(Bh[(size_t)s_src[j] * 128 + c]), num);
        den += sig;
        if (doE) { const float tv = en * s_sne[j]; psE += tv; pqE = fmaf(tv, tv, pqE); }
      }
      __syncthreads();
    }
    const float hv = (bf2f(Ah[(size_t)v * 128 + c]) + num / (den + 1e-6f)) * snorm_n[v];
    tbuf[(size_t)v * 128 + c] = hv;
    psH += hv; pqH = fmaf(hv, hv, pqH);
  }
  float* rep = statrep + (size_t)(blockIdx.x & (NREP - 1)) * 512;
  atomicAdd(rep + c,       psH);
  atomicAdd(rep + 128 + c, pqH);
  if (doE) {
    atomicAdd(rep + 256 + c, psE);
    atomicAdd(rep + 384 + c, pqE);
  }
}

// mu layout: [0]muH [128]invH [256]muE [384]invE
__global__ void finalize_kernel(const float* __restrict__ rep, float* __restrict__ mi,
                                float invN, float invE)
{
  const int c = threadIdx.x;
  float sH = 0.f, qH = 0.f, sE = 0.f, qE = 0.f;
  for (int r = 0; r < NREP; ++r) {
    const float* p = rep + (size_t)r * 512;
    sH += p[c]; qH += p[128 + c]; sE += p[256 + c]; qE += p[384 + c];
  }
  const float muH = sH * invN;
  const float vH  = fmaxf(qH * invN - muH * muH, 0.f);
  const float muE = sE * invE;
  const float vE  = fmaxf(qE * invE - muE * muE, 0.f);
  mi[c]       = muH;
  mi[128 + c] = rsqrtf(vH + 1e-5f);
  mi[256 + c] = muE;
  mi[384 + c] = rsqrtf(vE + 1e-5f);
}

// ============ BN apply + ReLU + residual ====================================
__global__ void node_apply(unsigned short* __restrict__ h, const float* __restrict__ tb,
                           const float* __restrict__ mi, const float* __restrict__ gn,
                           const float* __restrict__ bt, int M)
{
  const int total = M * 16;     // short8 chunks
  for (int i = blockIdx.x * blockDim.x + threadIdx.x; i < total; i += gridDim.x * blockDim.x) {
    const int row = i >> 4, c0 = (i & 15) * 8;
    const float* tp = tb + (size_t)row * 128 + c0;
    short8v hv = *(short8v*)(h + (size_t)i * 8);
#pragma unroll
    for (int j = 0; j < 8; ++j) {
      const int c = c0 + j;
      const float x = (tp[j] - mi[c]) * mi[128 + c] * gn[c] + bt[c];
      hv[j] = f2bf(bf2f((unsigned short)hv[j]) + fmaxf(x, 0.f));
    }
    *(short8v*)(h + (size_t)i * 8) = hv;
  }
}

__global__ void edge_apply(unsigned short* __restrict__ e, const unsigned short* __restrict__ enew,
                           const float* __restrict__ snorm, const float* __restrict__ mi,
                           const float* __restrict__ gn, const float* __restrict__ bt, int M)
{
  const int total = M * 16;
  for (int i = blockIdx.x * blockDim.x + threadIdx.x; i < total; i += gridDim.x * blockDim.x) {
    const int row = i >> 4, c0 = (i & 15) * 8;
    const float sn = snorm[row];
    const short8v tv = *(const short8v*)(enew + (size_t)i * 8);
    short8v ev = *(short8v*)(e + (size_t)i * 8);
#pragma unroll
    for (int j = 0; j < 8; ++j) {
      const int c = c0 + j;
      const float x = (bf2f((unsigned short)tv[j]) * sn - mi[256 + c]) * mi[384 + c] * gn[c] + bt[c];
      ev[j] = f2bf(bf2f((unsigned short)ev[j]) + fmaxf(x, 0.f));
    }
    *(short8v*)(e + (size_t)i * 8) = ev;
  }
}

// ============ readout =======================================================
__global__ void readout_scatter(const unsigned short* __restrict__ h, const int* __restrict__ gid,
                                float* __restrict__ gsum, int* __restrict__ gcnt, int N)
{
  const int c = threadIdx.x;            // 128
  const int row0 = blockIdx.x * 256;
  int cur = -1, cnt = 0;
  float s = 0.f;
  for (int r = 0; r < 256; ++r) {
    const int v = row0 + r;
    if (v >= N) break;
    const int g = gid[v];
    if (g != cur) {
      if (cur >= 0) {
        atomicAdd(&gsum[(size_t)cur * 128 + c], s);
        if (c == 0) atomicAdd(&gcnt[cur], cnt);
      }
      cur = g; s = 0.f; cnt = 0;
    }
    s += bf2f(h[(size_t)v * 128 + c]);
    ++cnt;
  }
  if (cur >= 0) {
    atomicAdd(&gsum[(size_t)cur * 128 + c], s);
    if (c == 0) atomicAdd(&gcnt[cur], cnt);
  }
}

__global__ void readout_final(const float* __restrict__ gsum, const int* __restrict__ gcnt,
                              const float* __restrict__ Wr, const float* __restrict__ br,
                              float* __restrict__ out)
{
  const int g = blockIdx.x;
  const int t = threadIdx.x;            // 128
  __shared__ float hg[128];
  const float cnt = fmaxf((float)gcnt[g], 1.f);
  hg[t] = gsum[(size_t)g * 128 + t] / cnt;
  __syncthreads();
  if (t < N_CLASS) {
    float acc = br[t];
    for (int k = 0; k < 128; ++k) acc = fmaf(hg[k], Wr[k * N_CLASS + t], acc);
    out[g * N_CLASS + t] = acc;
  }
}

// ============ launcher ======================================================
extern "C" void kernel_launch(void* const* d_in, const int* in_sizes, int n_in,
                              void* d_out, int out_size, void* d_ws, size_t ws_size,
                              hipStream_t stream)
{
  const float* h_in    = (const float*)d_in[0];
  const float* e_in    = (const float*)d_in[1];
  const float* snorm_n = (const float*)d_in[2];
  const float* snorm_e = (const float*)d_in[3];
  const int*   src     = (const int*)d_in[4];
  const int*   dst     = (const int*)d_in[5];
  const int*   gid     = (const int*)d_in[6];
  const float* Wh_emb  = (const float*)d_in[7];
  const float* bh_emb  = (const float*)d_in[8];
  const float* We_emb  = (const float*)d_in[9];
  const float* be_emb  = (const float*)d_in[10];
  const float* WA = (const float*)d_in[11]; const float* bA = (const float*)d_in[12];
  const float* WB = (const float*)d_in[13]; const float* bB = (const float*)d_in[14];
  const float* WC = (const float*)d_in[15]; const float* bC = (const float*)d_in[16];
  const float* WD = (const float*)d_in[17]; const float* bD = (const float*)d_in[18];
  const float* WE = (const float*)d_in[19]; const float* bE = (const float*)d_in[20];
  const float* gn_h = (const float*)d_in[21]; const float* bt_h = (const float*)d_in[22];
  const float* gn_e = (const float*)d_in[23]; const float* bt_e = (const float*)d_in[24];
  const float* Wr = (const float*)d_in[25]; const float* br = (const float*)d_in[26];
  float* out = (float*)d_out;
  (void)in_sizes; (void)n_in; (void)out_size; (void)ws_size;

  char* ws = (char*)d_ws;
  size_t off = 0;
  auto alloc = [&](size_t bytes) -> char* {
    off = (off + 255) & ~(size_t)255;
    char* p = ws + off;
    off += bytes;
    return p;
  };
  const size_t ND = (size_t)N_NODES * 128, ED = (size_t)N_EDGES * 128;
  unsigned short* hbuf = (unsigned short*)alloc(ND * 2);
  unsigned short* ebuf = (unsigned short*)alloc(ED * 2);
  unsigned short* enew = (unsigned short*)alloc(ED * 2);
  unsigned short* Ah   = (unsigned short*)alloc(ND * 2);
  unsigned short* Bh   = (unsigned short*)alloc(ND * 2);
  unsigned short* Dh   = (unsigned short*)alloc(ND * 2);
  unsigned short* Eh   = (unsigned short*)alloc(ND * 2);
  float* tbuf          = (float*)alloc(ND * 4);
  unsigned short* Wt   = (unsigned short*)alloc((size_t)17 * 16384 * 2);
  float* statrep       = (float*)alloc((size_t)NREP * 512 * 4);
  float* mu            = (float*)alloc(512 * 4);
  int* cnt    = (int*)alloc((size_t)N_NODES * 4);
  int* start  = (int*)alloc((size_t)(N_NODES + 1) * 4);
  int* cursor = (int*)alloc((size_t)N_NODES * 4);
  int* csr    = (int*)alloc((size_t)N_EDGES * 4);
  float* gsum = (float*)alloc((size_t)N_GRAPHS * 128 * 4);
  int* gcnt   = (int*)alloc((size_t)N_GRAPHS * 4);

  // weights -> bf16 transposed
  wconv<<<17 * 64, 256, 0, stream>>>(Wh_emb, We_emb, WA, WB, WC, WD, WE, Wt);

  // CSR by dst
  hipMemsetAsync(cnt, 0, (size_t)N_NODES * 4, stream);
  hist_kernel<<<(N_EDGES + 255) / 256, 256, 0, stream>>>(dst, cnt, N_EDGES);
  scan_kernel<<<1, 1024, 0, stream>>>(cnt, start, cursor, N_NODES, N_EDGES);
  scatter_kernel<<<(N_EDGES + 255) / 256, 256, 0, stream>>>(dst, cursor, csr, N_EDGES);

  const int gbN = (N_NODES + 63) / 64;   // 469
  const int gbE = N_EDGES / 64;          // 7500

  // input embeddings (fp32 A -> bf16 out)
  {
    GemmArgs g{};
    g.Wt[0] = Wt + 0 * 16384; g.bias[0] = bh_emb; g.out[0] = hbuf;
    gemm_mm<1, true><<<gbN, 256, 0, stream>>>(h_in, g, N_NODES);
    g.Wt[0] = Wt + 1 * 16384; g.bias[0] = be_emb; g.out[0] = ebuf;
    gemm_mm<1, true><<<gbE, 256, 0, stream>>>(e_in, g, N_EDGES);
  }

  for (int l = 0; l < N_LAYERS; ++l) {
    const size_t bOff = (size_t)l * 128;
    const int doE = (l < N_LAYERS - 1) ? 1 : 0;
    // fused node GEMMs: Ah,Bh,Dh,Eh
    {
      GemmArgs g{};
      g.Wt[0] = Wt + (size_t)(2 + l)  * 16384; g.bias[0] = bA + bOff; g.out[0] = Ah;
      g.Wt[1] = Wt + (size_t)(5 + l)  * 16384; g.bias[1] = bB + bOff; g.out[1] = Bh;
      g.Wt[2] = Wt + (size_t)(11 + l) * 16384; g.bias[2] = bD + bOff; g.out[2] = Dh;
      g.Wt[3] = Wt + (size_t)(14 + l) * 16384; g.bias[3] = bE + bOff; g.out[3] = Eh;
      gemm_mm<4, false><<<gbN, 256, 0, stream>>>(hbuf, g, N_NODES);
    }
    // edge GEMM + message fuse
    gemm_edge<<<gbE, 256, 0, stream>>>(ebuf, Wt + (size_t)(8 + l) * 16384, bC + bOff,
                                       Dh, Eh, src, dst, enew);
    // gated reduce + BN stats
    hipMemsetAsync(statrep, 0, (size_t)NREP * 512 * 4, stream);
    aggregate<<<N_NODES / 8, 128, 0, stream>>>(enew, Bh, Ah, snorm_n, snorm_e,
                                               start, csr, src, tbuf, statrep, doE);
    finalize_kernel<<<1, 128, 0, stream>>>(statrep, mu, 1.f / N_NODES, 1.f / N_EDGES);
    // BN apply + ReLU + residual
    node_apply<<<1875, 256, 0, stream>>>(hbuf, tbuf, mu, gn_h + bOff, bt_h + bOff, N_NODES);
    if (doE)
      edge_apply<<<2048, 256, 0, stream>>>(ebuf, enew, snorm_e, mu, gn_e + bOff, bt_e + bOff, N_EDGES);
  }

  // readout
  hipMemsetAsync(gsum, 0, (size_t)N_GRAPHS * 128 * 4, stream);
  hipMemsetAsync(gcnt, 0, (size_t)N_GRAPHS * 4, stream);
  readout_scatter<<<(N_NODES + 255) / 256, 128, 0, stream>>>(hbuf, gid, gsum, gcnt, N_NODES);
  readout_final<<<N_GRAPHS, 128, 0, stream>>>(gsum, gcnt, Wr, br, out);
}

// Round 3
// 901.986 us; speedup vs baseline: 2.9072x; 1.6540x over previous
//
#include <hip/hip_runtime.h>
#include <cstdint>
#include <cstddef>

#define N_NODES  30000
#define N_EDGES  480000
#define N_LAYERS 3
#define N_GRAPHS 64
#define N_CLASS  10
#define NREP     32

typedef __attribute__((ext_vector_type(8))) short short8v;   // 8 bf16 (4 VGPR)
typedef __attribute__((ext_vector_type(4))) float f32x4;

__device__ __forceinline__ unsigned short f2bf(float x) {
  union { float f; unsigned u; } v; v.f = x;
  unsigned r = v.u + 0x7FFFu + ((v.u >> 16) & 1u);   // RNE
  return (unsigned short)(r >> 16);
}
__device__ __forceinline__ float bf2f(unsigned short h) {
  union { unsigned u; float f; } v; v.u = ((unsigned)h) << 16;
  return v.f;
}
// XOR-swizzle for a [128][128] bf16 LDS tile (256 B rows): kills the 16-way
// bank conflict on ds_read_b128 column-slice reads (guide §6 G4).
__device__ __forceinline__ int swzW(int row, int off16) {
  return (row << 8) | (off16 ^ ((row & 7) << 4));
}

// ============ weight convert + transpose: Wt[mi][n][k] = bf16(W[k][n]) ======
// mi: 0=Wh_emb 1=We_emb 2+l=WA 5+l=WB 8+l=WC 11+l=WD 14+l=WE
__global__ void wconv(const float* __restrict__ Wh, const float* __restrict__ We,
                      const float* __restrict__ WA, const float* __restrict__ WB,
                      const float* __restrict__ WC, const float* __restrict__ WD,
                      const float* __restrict__ WE, unsigned short* __restrict__ Wt)
{
  const int mi  = blockIdx.x >> 6;
  const int idx = (blockIdx.x & 63) * 256 + threadIdx.x;   // 0..16383
  const float* src;
  if      (mi == 0) src = Wh;
  else if (mi == 1) src = We;
  else if (mi < 5)  src = WA + (size_t)(mi - 2) * 16384;
  else if (mi < 8)  src = WB + (size_t)(mi - 5) * 16384;
  else if (mi < 11) src = WC + (size_t)(mi - 8) * 16384;
  else if (mi < 14) src = WD + (size_t)(mi - 11) * 16384;
  else              src = WE + (size_t)(mi - 14) * 16384;
  const int k = idx >> 7, n = idx & 127;
  Wt[(size_t)mi * 16384 + (size_t)n * 128 + k] = f2bf(src[idx]);
}

// ============ MFMA GEMM: out_m = A @ W_m + b_m (NMAT outputs share A) =======
struct GemmArgs {
  const unsigned short* Wt[4];
  const float* bias[4];
  unsigned short* out[4];
};

template<int NMAT, bool AFP32>
__global__ __launch_bounds__(256)
void gemm_mm(const void* __restrict__ Ap, GemmArgs g, int M)
{
  __shared__ __align__(16) unsigned char WL[32768];   // W swizzled; reused as [64][136] u16 transpose buf
  unsigned short* Wl = (unsigned short*)WL;
  const int t = threadIdx.x;
  const int w = t >> 6, l = t & 63;
  const int lr = l & 15, lkb = (l >> 4) * 8;
  const int r0 = blockIdx.x * 64;
  int arow = r0 + w * 16 + lr; if (arow >= M) arow = M - 1;

  short8v a[4];
  if (AFP32) {
    const float* A = (const float*)Ap;
#pragma unroll
    for (int kk = 0; kk < 4; ++kk) {
      const float* p = A + (size_t)arow * 128 + kk * 32 + lkb;
      const float4 u = *(const float4*)p;
      const float4 v = *(const float4*)(p + 4);
      short8v av;
      av[0]=f2bf(u.x); av[1]=f2bf(u.y); av[2]=f2bf(u.z); av[3]=f2bf(u.w);
      av[4]=f2bf(v.x); av[5]=f2bf(v.y); av[6]=f2bf(v.z); av[7]=f2bf(v.w);
      a[kk] = av;
    }
  } else {
    const unsigned short* A = (const unsigned short*)Ap;
#pragma unroll
    for (int kk = 0; kk < 4; ++kk)
      a[kk] = *(const short8v*)(A + (size_t)arow * 128 + kk * 32 + lkb);
  }

#pragma unroll
  for (int m = 0; m < NMAT; ++m) {
    if (m) __syncthreads();
    // stage W_m into LDS (swizzled), coalesced 16 B/lane
#pragma unroll
    for (int p = 0; p < 8; ++p) {
      const int ci = t + p * 256;
      *(short8v*)(WL + swzW(ci >> 4, (ci & 15) * 16)) = *(const short8v*)(g.Wt[m] + (size_t)ci * 8);
    }
    __syncthreads();
    f32x4 acc[8];
#pragma unroll
    for (int ct = 0; ct < 8; ++ct) acc[ct] = (f32x4){0.f, 0.f, 0.f, 0.f};
#pragma unroll
    for (int kk = 0; kk < 4; ++kk)
#pragma unroll
      for (int ct = 0; ct < 8; ++ct) {
        const short8v b = *(const short8v*)(WL + swzW(ct * 16 + lr, kk * 64 + (l >> 4) * 16));
        acc[ct] = __builtin_amdgcn_mfma_f32_16x16x32_bf16(a[kk], b, acc[ct], 0, 0, 0);
      }
    __syncthreads();
    // transpose through LDS (+bias), bf16
#pragma unroll
    for (int ct = 0; ct < 8; ++ct) {
      const float bb = g.bias[m][ct * 16 + lr];
#pragma unroll
      for (int q = 0; q < 4; ++q)
        Wl[(w * 16 + (l >> 4) * 4 + q) * 136 + ct * 16 + lr] = f2bf(acc[ct][q] + bb);
    }
    __syncthreads();
    unsigned short* out = g.out[m];
#pragma unroll
    for (int p = 0; p < 4; ++p) {
      const int ci = t + p * 256;
      const int rr = ci >> 4, co = (ci & 15) * 8;
      const int grow = r0 + rr;
      if (grow < M)
        *(short8v*)(out + (size_t)grow * 128 + co) = *(const short8v*)(Wl + rr * 136 + co);
    }
  }
}

// ============ fused edge kernel =============================================
// LMODE 0: A = eres rows (layer 0)
// LMODE 1: A = eres + relu(BN(enew_prev)) via pq; write updated eres
// LMODE 2: same as 1 but eres write skipped (dead after last layer)
// Then enew = A@WC + bC + Dh[src] + Eh[dst], coalesced short8v stores.
template<int LMODE>
__global__ __launch_bounds__(256)
void edge_fused(unsigned short* __restrict__ eres, unsigned short* __restrict__ enew,
                const unsigned short* __restrict__ WtC, const float* __restrict__ bC,
                const unsigned short* __restrict__ Dh, const unsigned short* __restrict__ Eh,
                const int* __restrict__ src, const int* __restrict__ dst,
                const float* __restrict__ snorm_e, const float2* __restrict__ pq)
{
  __shared__ __align__(16) unsigned char WL[32768];
  __shared__ float2 pql[128];
  unsigned short* Wl = (unsigned short*)WL;
  const int t = threadIdx.x;
  const int w = t >> 6, l = t & 63;
  const int lr = l & 15, lkb = (l >> 4) * 8;
  const int r0 = blockIdx.x * 64;                 // E % 64 == 0
  if (LMODE >= 1 && t < 128) pql[t] = pq[t];
#pragma unroll
  for (int p = 0; p < 8; ++p) {
    const int ci = t + p * 256;
    *(short8v*)(WL + swzW(ci >> 4, (ci & 15) * 16)) = *(const short8v*)(WtC + (size_t)ci * 8);
  }
  __syncthreads();

  const int arow = r0 + w * 16 + lr;
  short8v a[4];
  if (LMODE == 0) {
#pragma unroll
    for (int kk = 0; kk < 4; ++kk)
      a[kk] = *(const short8v*)(eres + (size_t)arow * 128 + kk * 32 + lkb);
  } else {
    const float sn = snorm_e[arow];
#pragma unroll
    for (int kk = 0; kk < 4; ++kk) {
      const short8v ep = *(const short8v*)(enew + (size_t)arow * 128 + kk * 32 + lkb);
      const short8v er = *(const short8v*)(eres + (size_t)arow * 128 + kk * 32 + lkb);
      short8v av;
#pragma unroll
      for (int j = 0; j < 8; ++j) {
        const float2 PQ = pql[kk * 32 + lkb + j];
        const float x = bf2f((unsigned short)ep[j]) * sn * PQ.x + PQ.y;
        av[j] = (short)f2bf(bf2f((unsigned short)er[j]) + fmaxf(x, 0.f));
      }
      a[kk] = av;
      if (LMODE == 1)
        *(short8v*)(eres + (size_t)arow * 128 + kk * 32 + lkb) = av;
    }
  }

  f32x4 acc[8];
#pragma unroll
  for (int ct = 0; ct < 8; ++ct) acc[ct] = (f32x4){0.f, 0.f, 0.f, 0.f};
#pragma unroll
  for (int kk = 0; kk < 4; ++kk)
#pragma unroll
    for (int ct = 0; ct < 8; ++ct) {
      const short8v b = *(const short8v*)(WL + swzW(ct * 16 + lr, kk * 64 + (l >> 4) * 16));
      acc[ct] = __builtin_amdgcn_mfma_f32_16x16x32_bf16(a[kk], b, acc[ct], 0, 0, 0);
    }
  __syncthreads();
#pragma unroll
  for (int ct = 0; ct < 8; ++ct) {
    const float bb = bC[ct * 16 + lr];
#pragma unroll
    for (int q = 0; q < 4; ++q)
      Wl[(w * 16 + (l >> 4) * 4 + q) * 136 + ct * 16 + lr] = f2bf(acc[ct][q] + bb);
  }
  __syncthreads();
#pragma unroll
  for (int p = 0; p < 4; ++p) {
    const int ci = t + p * 256;
    const int rr = ci >> 4, co = (ci & 15) * 8;
    const int edge = r0 + rr;
    const int s = src[edge], d = dst[edge];
    const short8v ce = *(const short8v*)(Wl + rr * 136 + co);
    const short8v dv = *(const short8v*)(Dh + (size_t)s * 128 + co);
    const short8v ev = *(const short8v*)(Eh + (size_t)d * 128 + co);
    short8v ov;
#pragma unroll
    for (int j = 0; j < 8; ++j)
      ov[j] = (short)f2bf(bf2f((unsigned short)ce[j]) + bf2f((unsigned short)dv[j]) + bf2f((unsigned short)ev[j]));
    *(short8v*)(enew + (size_t)edge * 128 + co) = ov;
  }
}

// ============ CSR build =====================================================
__global__ void hist_kernel(const int* __restrict__ dst, int* __restrict__ cnt, int E)
{
  const int i = blockIdx.x * 256 + threadIdx.x;
  if (i < E) atomicAdd(&cnt[dst[i]], 1);
}

__global__ void scan_kernel(const int* __restrict__ cnt, int* __restrict__ start,
                            int* __restrict__ cursor, int n, int total)
{
  __shared__ int lds[1024];
  const int tid = threadIdx.x;
  const int chunk = (n + 1023) / 1024;
  const int lo = tid * chunk, hi = min(lo + chunk, n);
  int s = 0;
  for (int i = lo; i < hi; ++i) s += cnt[i];
  lds[tid] = s;
  __syncthreads();
  for (int off = 1; off < 1024; off <<= 1) {
    const int v = (tid >= off) ? lds[tid - off] : 0;
    __syncthreads();
    lds[tid] += v;
    __syncthreads();
  }
  int run = (tid == 0) ? 0 : lds[tid - 1];
  for (int i = lo; i < hi; ++i) { start[i] = run; cursor[i] = run; run += cnt[i]; }
  if (tid == 0) start[n] = total;
}

__global__ void scatter_kernel(const int* __restrict__ dst, int* __restrict__ cursor,
                               int* __restrict__ csr, int E)
{
  const int i = blockIdx.x * 256 + threadIdx.x;
  if (i < E) { const int p = atomicAdd(&cursor[dst[i]], 1); csr[p] = i; }
}

// ============ aggregate: gated reduce + BN stats (h and e) ==================
// 16 nodes/block; 16 lanes per node row (short8v = 16 B/lane vector loads).
__global__ __launch_bounds__(256)
void aggregate(const unsigned short* __restrict__ enew, const unsigned short* __restrict__ Bh,
               const unsigned short* __restrict__ Ah, const float* __restrict__ snorm_n,
               const float* __restrict__ snorm_e, const int* __restrict__ start,
               const int* __restrict__ csr, const int* __restrict__ src,
               float* __restrict__ tbuf, float* __restrict__ statrep, int doE)
{
  __shared__ float2 red[16][132];
  const int t = threadIdx.x;
  const int g = t >> 4, q = t & 15;
  const int v = blockIdx.x * 16 + g;             // N % 16 == 0
  const int s0 = start[v], s1 = start[v + 1];
  float num[8] = {0,0,0,0,0,0,0,0}, den[8] = {0,0,0,0,0,0,0,0};
  float psE[8] = {0,0,0,0,0,0,0,0}, pqE[8] = {0,0,0,0,0,0,0,0};

  float sn = 0.f;
  short8v ev = {}, bv = {};
  if (s0 < s1) {
    const int eid = csr[s0];
    const int sv  = src[eid];
    sn = snorm_e[eid];
    ev = *(const short8v*)(enew + (size_t)eid * 128 + q * 8);
    bv = *(const short8v*)(Bh + (size_t)sv * 128 + q * 8);
  }
  for (int i = s0; i < s1; ++i) {
    float snn = 0.f;
    short8v evn = {}, bvn = {};
    if (i + 1 < s1) {                            // prefetch next edge
      const int eid = csr[i + 1];
      const int sv  = src[eid];
      snn = snorm_e[eid];
      evn = *(const short8v*)(enew + (size_t)eid * 128 + q * 8);
      bvn = *(const short8v*)(Bh + (size_t)sv * 128 + q * 8);
    }
#pragma unroll
    for (int j = 0; j < 8; ++j) {
      const float en = bf2f((unsigned short)ev[j]);
      const float sg = 1.f / (1.f + __expf(-en));
      num[j] = fmaf(sg, bf2f((unsigned short)bv[j]), num[j]);
      den[j] += sg;
      if (doE) { const float tv = en * sn; psE[j] += tv; pqE[j] = fmaf(tv, tv, pqE[j]); }
    }
    ev = evn; bv = bvn; sn = snn;
  }
  const float snv = snorm_n[v];
  const short8v av = *(const short8v*)(Ah + (size_t)v * 128 + q * 8);
  float hv[8];
#pragma unroll
  for (int j = 0; j < 8; ++j)
    hv[j] = (bf2f((unsigned short)av[j]) + num[j] / (den[j] + 1e-6f)) * snv;
  *(float4*)(tbuf + (size_t)v * 128 + q * 8)     = make_float4(hv[0], hv[1], hv[2], hv[3]);
  *(float4*)(tbuf + (size_t)v * 128 + q * 8 + 4) = make_float4(hv[4], hv[5], hv[6], hv[7]);

  float* rep = statrep + (size_t)(blockIdx.x & (NREP - 1)) * 512;
#pragma unroll
  for (int j = 0; j < 8; ++j) red[g][q * 8 + j] = make_float2(hv[j], hv[j] * hv[j]);
  __syncthreads();
  if (t < 128) {
    float s = 0.f, qq = 0.f;
    for (int gg = 0; gg < 16; ++gg) { s += red[gg][t].x; qq += red[gg][t].y; }
    atomicAdd(rep + t, s); atomicAdd(rep + 128 + t, qq);
  }
  if (doE) {
    __syncthreads();
#pragma unroll
    for (int j = 0; j < 8; ++j) red[g][q * 8 + j] = make_float2(psE[j], pqE[j]);
    __syncthreads();
    if (t < 128) {
      float s = 0.f, qq = 0.f;
      for (int gg = 0; gg < 16; ++gg) { s += red[gg][t].x; qq += red[gg][t].y; }
      atomicAdd(rep + 256 + t, s); atomicAdd(rep + 384 + t, qq);
    }
  }
}

// mu: [0..127]=muH [128..255]=invH ; pq[c] = {P, Q} for NEXT layer's edge apply
__global__ void finalize_kernel(const float* __restrict__ rep, float* __restrict__ mu,
                                float2* __restrict__ pq, const float* __restrict__ gn_e_l,
                                const float* __restrict__ bt_e_l, float invN, float invE)
{
  const int c = threadIdx.x;
  float sH = 0.f, qH = 0.f, sE = 0.f, qE = 0.f;
  for (int r = 0; r < NREP; ++r) {
    const float* p = rep + (size_t)r * 512;
    sH += p[c]; qH += p[128 + c]; sE += p[256 + c]; qE += p[384 + c];
  }
  const float muH = sH * invN;
  const float vH  = fmaxf(qH * invN - muH * muH, 0.f);
  mu[c]       = muH;
  mu[128 + c] = rsqrtf(vH + 1e-5f);
  const float muE = sE * invE;
  const float vE  = fmaxf(qE * invE - muE * muE, 0.f);
  const float P   = rsqrtf(vE + 1e-5f) * gn_e_l[c];
  pq[c] = make_float2(P, bt_e_l[c] - muE * P);
}

// ============ node BN apply + ReLU + residual ===============================
__global__ __launch_bounds__(256)
void node_apply(unsigned short* __restrict__ h, const float* __restrict__ tb,
                const float* __restrict__ mu, const float* __restrict__ gn,
                const float* __restrict__ bt)
{
  const int i = blockIdx.x * 256 + threadIdx.x;      // N*16 chunks exactly
  const int c0 = (i & 15) * 8;
  const float* tp = tb + (size_t)i * 8;
  short8v hv = *(short8v*)(h + (size_t)i * 8);
#pragma unroll
  for (int j = 0; j < 8; ++j) {
    const int c = c0 + j;
    const float x = (tp[j] - mu[c]) * mu[128 + c] * gn[c] + bt[c];
    hv[j] = (short)f2bf(bf2f((unsigned short)hv[j]) + fmaxf(x, 0.f));
  }
  *(short8v*)(h + (size_t)i * 8) = hv;
}

// ============ readout =======================================================
__global__ void readout_scatter(const unsigned short* __restrict__ h, const int* __restrict__ gid,
                                float* __restrict__ gsum, int* __restrict__ gcnt, int N)
{
  const int c = threadIdx.x;            // 128
  const int row0 = blockIdx.x * 256;
  int cur = -1, cnt = 0;
  float s = 0.f;
  for (int r = 0; r < 256; ++r) {
    const int v = row0 + r;
    if (v >= N) break;
    const int g = gid[v];
    if (g != cur) {
      if (cur >= 0) {
        atomicAdd(&gsum[(size_t)cur * 128 + c], s);
        if (c == 0) atomicAdd(&gcnt[cur], cnt);
      }
      cur = g; s = 0.f; cnt = 0;
    }
    s += bf2f(h[(size_t)v * 128 + c]);
    ++cnt;
  }
  if (cur >= 0) {
    atomicAdd(&gsum[(size_t)cur * 128 + c], s);
    if (c == 0) atomicAdd(&gcnt[cur], cnt);
  }
}

__global__ void readout_final(const float* __restrict__ gsum, const int* __restrict__ gcnt,
                              const float* __restrict__ Wr, const float* __restrict__ br,
                              float* __restrict__ out)
{
  const int g = blockIdx.x;
  const int t = threadIdx.x;            // 128
  __shared__ float hg[128];
  const float cnt = fmaxf((float)gcnt[g], 1.f);
  hg[t] = gsum[(size_t)g * 128 + t] / cnt;
  __syncthreads();
  if (t < N_CLASS) {
    float acc = br[t];
    for (int k = 0; k < 128; ++k) acc = fmaf(hg[k], Wr[k * N_CLASS + t], acc);
    out[g * N_CLASS + t] = acc;
  }
}

// ============ launcher ======================================================
extern "C" void kernel_launch(void* const* d_in, const int* in_sizes, int n_in,
                              void* d_out, int out_size, void* d_ws, size_t ws_size,
                              hipStream_t stream)
{
  const float* h_in    = (const float*)d_in[0];
  const float* e_in    = (const float*)d_in[1];
  const float* snorm_n = (const float*)d_in[2];
  const float* snorm_e = (const float*)d_in[3];
  const int*   src     = (const int*)d_in[4];
  const int*   dst     = (const int*)d_in[5];
  const int*   gid     = (const int*)d_in[6];
  const float* Wh_emb  = (const float*)d_in[7];
  const float* bh_emb  = (const float*)d_in[8];
  const float* We_emb  = (const float*)d_in[9];
  const float* be_emb  = (const float*)d_in[10];
  const float* WA = (const float*)d_in[11]; const float* bA = (const float*)d_in[12];
  const float* WB = (const float*)d_in[13]; const float* bB = (const float*)d_in[14];
  const float* WC = (const float*)d_in[15]; const float* bC = (const float*)d_in[16];
  const float* WD = (const float*)d_in[17]; const float* bD = (const float*)d_in[18];
  const float* WE = (const float*)d_in[19]; const float* bE = (const float*)d_in[20];
  const float* gn_h = (const float*)d_in[21]; const float* bt_h = (const float*)d_in[22];
  const float* gn_e = (const float*)d_in[23]; const float* bt_e = (const float*)d_in[24];
  const float* Wr = (const float*)d_in[25]; const float* br = (const float*)d_in[26];
  float* out = (float*)d_out;
  (void)in_sizes; (void)n_in; (void)out_size; (void)ws_size;

  char* ws = (char*)d_ws;
  size_t off = 0;
  auto alloc = [&](size_t bytes) -> char* {
    off = (off + 255) & ~(size_t)255;
    char* p = ws + off;
    off += bytes;
    return p;
  };
  const size_t ND = (size_t)N_NODES * 128, ED = (size_t)N_EDGES * 128;
  unsigned short* hbuf = (unsigned short*)alloc(ND * 2);
  unsigned short* ebuf = (unsigned short*)alloc(ED * 2);   // residual e
  unsigned short* enew = (unsigned short*)alloc(ED * 2);   // pre-BN e_new
  unsigned short* Ah   = (unsigned short*)alloc(ND * 2);
  unsigned short* Bh   = (unsigned short*)alloc(ND * 2);
  unsigned short* Dh   = (unsigned short*)alloc(ND * 2);
  unsigned short* Eh   = (unsigned short*)alloc(ND * 2);
  float* tbuf          = (float*)alloc(ND * 4);
  unsigned short* Wt   = (unsigned short*)alloc((size_t)17 * 16384 * 2);
  float* statrep       = (float*)alloc((size_t)NREP * 512 * 4);
  float* mu            = (float*)alloc(256 * 4);
  float2* pq           = (float2*)alloc(128 * 8);
  int* cnt    = (int*)alloc((size_t)N_NODES * 4);
  int* start  = (int*)alloc((size_t)(N_NODES + 1) * 4);
  int* cursor = (int*)alloc((size_t)N_NODES * 4);
  int* csr    = (int*)alloc((size_t)N_EDGES * 4);
  float* gsum = (float*)alloc((size_t)N_GRAPHS * 128 * 4);
  int* gcnt   = (int*)alloc((size_t)N_GRAPHS * 4);

  // weights -> bf16 transposed
  wconv<<<17 * 64, 256, 0, stream>>>(Wh_emb, We_emb, WA, WB, WC, WD, WE, Wt);

  // CSR by dst
  hipMemsetAsync(cnt, 0, (size_t)N_NODES * 4, stream);
  hist_kernel<<<(N_EDGES + 255) / 256, 256, 0, stream>>>(dst, cnt, N_EDGES);
  scan_kernel<<<1, 1024, 0, stream>>>(cnt, start, cursor, N_NODES, N_EDGES);
  scatter_kernel<<<(N_EDGES + 255) / 256, 256, 0, stream>>>(dst, cursor, csr, N_EDGES);

  const int gbN = (N_NODES + 63) / 64;   // 469
  const int gbE = N_EDGES / 64;          // 7500

  // input embeddings (fp32 A -> bf16 out)
  {
    GemmArgs g{};
    g.Wt[0] = Wt + 0 * 16384; g.bias[0] = bh_emb; g.out[0] = hbuf;
    gemm_mm<1, true><<<gbN, 256, 0, stream>>>(h_in, g, N_NODES);
    g.Wt[0] = Wt + 1 * 16384; g.bias[0] = be_emb; g.out[0] = ebuf;
    gemm_mm<1, true><<<gbE, 256, 0, stream>>>(e_in, g, N_EDGES);
  }

  for (int l = 0; l < N_LAYERS; ++l) {
    const size_t bOff = (size_t)l * 128;
    const int doE = (l < N_LAYERS - 1) ? 1 : 0;
    // fused node GEMMs: Ah,Bh,Dh,Eh
    {
      GemmArgs g{};
      g.Wt[0] = Wt + (size_t)(2 + l)  * 16384; g.bias[0] = bA + bOff; g.out[0] = Ah;
      g.Wt[1] = Wt + (size_t)(5 + l)  * 16384; g.bias[1] = bB + bOff; g.out[1] = Bh;
      g.Wt[2] = Wt + (size_t)(11 + l) * 16384; g.bias[2] = bD + bOff; g.out[2] = Dh;
      g.Wt[3] = Wt + (size_t)(14 + l) * 16384; g.bias[3] = bE + bOff; g.out[3] = Eh;
      gemm_mm<4, false><<<gbN, 256, 0, stream>>>(hbuf, g, N_NODES);
    }
    // fused edge kernel (BN-apply of prev layer folded into A-load)
    const unsigned short* WtC = Wt + (size_t)(8 + l) * 16384;
    if (l == 0)
      edge_fused<0><<<gbE, 256, 0, stream>>>(ebuf, enew, WtC, bC + bOff, Dh, Eh, src, dst, snorm_e, pq);
    else if (l == 1)
      edge_fused<1><<<gbE, 256, 0, stream>>>(ebuf, enew, WtC, bC + bOff, Dh, Eh, src, dst, snorm_e, pq);
    else
      edge_fused<2><<<gbE, 256, 0, stream>>>(ebuf, enew, WtC, bC + bOff, Dh, Eh, src, dst, snorm_e, pq);
    // gated reduce + BN stats
    hipMemsetAsync(statrep, 0, (size_t)NREP * 512 * 4, stream);
    aggregate<<<N_NODES / 16, 256, 0, stream>>>(enew, Bh, Ah, snorm_n, snorm_e,
                                                start, csr, src, tbuf, statrep, doE);
    finalize_kernel<<<1, 128, 0, stream>>>(statrep, mu, pq, gn_e + bOff, bt_e + bOff,
                                           1.f / N_NODES, 1.f / N_EDGES);
    node_apply<<<N_NODES / 16, 256, 0, stream>>>(hbuf, tbuf, mu, gn_h + bOff, bt_h + bOff);
  }

  // readout
  hipMemsetAsync(gsum, 0, (size_t)N_GRAPHS * 128 * 4, stream);
  hipMemsetAsync(gcnt, 0, (size_t)N_GRAPHS * 4, stream);
  readout_scatter<<<(N_NODES + 255) / 256, 128, 0, stream>>>(hbuf, gid, gsum, gcnt, N_NODES);
  readout_final<<<N_GRAPHS, 128, 0, stream>>>(gsum, gcnt, Wr, br, out);
}